// Round 4
// baseline (228.810 us; speedup 1.0000x reference)
//
#include <hip/hip_runtime.h>

// QKV attention: qkv [B=64, 3*64, T=2048] fp32 -> out [64, 64, 2048] fp32.
// Round 11: occupancy + barrier attack after r10 post-mortem.
//  - r10: attn 104us, MfmaUtil 28, VALUBusy 31, Occ 19.7% -> >55% of cycles
//    NO pipe issues. Grid was the binding limit (512 blocks = 2 blocks/CU =
//    2 waves/SIMD, barrier-locked). VGPR/LDS had headroom.
//  - BQ 256->128: wave owns 32 queries (nb dim deleted). Grid 1024 ->
//    4 blocks/CU = 4 waves/SIMD. launch_bounds (256,4).
//  - K/V tiles double-buffered (32KB LDS): tile i writes buf[i&1], whose
//    last reader was tile i-2 (two barriers ago) -> ONE barrier per tile
//    (was 2), staging never waits on prior compute.
//  - XCD swizzle re-derived for 1024 blocks: 16 query-blocks of head b ->
//    XCD b&7 (K fp16 262KB + V fp32 524KB per head stay L2-hot).
//  - Compute core unchanged from r10 (verified): 32x32 MFMA, S^T layout,
//    exp2 with pre-folded scale, pkrtz + v_permlane32_swap_b32 in-register
//    P rebuild (P never touches LDS), prep_k for K transpose.
// NOTE: v_cvt_pk_bf16_f32 inline asm proven wrong on HW (r3/4/5) - banned.

#define DHEAD 64
#define TLEN  2048
#define NB    64
#define BQ    128
#define BK    64
#define NT    (TLEN / BK)
#define LDT   65      // prep fp32 transpose leading dim

typedef _Float16 h16x8 __attribute__((ext_vector_type(8)));
typedef _Float16 h16x2 __attribute__((ext_vector_type(2)));
typedef __fp16   fp16x2 __attribute__((ext_vector_type(2)));
typedef float    f32x16 __attribute__((ext_vector_type(16)));

// 1/sqrt(sqrt(64)) * sqrt(log2(e)): applied to Q and K; scores arrive
// pre-scaled for exp2.
#define QK_SCALE 0.42466090267246895f

extern "C" __device__ float __ocml_native_exp2_f32(float);

union H2U  { h16x2 h; fp16x2 f; unsigned u; };
union FRAG { h16x8 v; unsigned u[4]; };

__device__ __forceinline__ unsigned pk_u(float a, float b) {
    H2U x; x.f = __builtin_amdgcn_cvt_pkrtz(a, b); return x.u;   // v_cvt_pkrtz_f16_f32
}

// fp16 tile [row][64]: 8-elem (16B) granule XOR swizzle keyed on row&7.
__device__ __forceinline__ int swz(int row, int col) {
    return row * 64 + (col ^ ((row & 7) << 3));
}

// ---------- prep: K -> fp16 [b][s][c] (transposed, pre-scaled) ----------
__global__ __launch_bounds__(256)
void prep_k(const float* __restrict__ qkv, _Float16* __restrict__ ws) {
    __shared__ float T32[64 * LDT];
    const int tile = blockIdx.x, b = blockIdx.y;
    const int tid = threadIdx.x;
    const float* src = qkv + ((size_t)b * 3 + 1) * DHEAD * TLEN + tile * 64;
    _Float16* dst = ws + (size_t)b * DHEAD * TLEN + (size_t)tile * 64 * DHEAD;
    {
        int c = tid >> 4, t4 = (tid & 15) * 4;
        #pragma unroll
        for (int rr = 0; rr < 4; ++rr, c += 16) {
            float4 f = *(const float4*)(src + c * TLEN + t4);
            T32[(t4 + 0) * LDT + c] = f.x;
            T32[(t4 + 1) * LDT + c] = f.y;
            T32[(t4 + 2) * LDT + c] = f.z;
            T32[(t4 + 3) * LDT + c] = f.w;
        }
    }
    __syncthreads();
    #pragma unroll
    for (int rep = 0; rep < 2; ++rep) {
        int idx = rep * 256 + tid;
        int t = idx >> 3, j = idx & 7;
        const float* row = &T32[t * LDT + j * 8];
        FRAG o;
        o.u[0] = pk_u(row[0] * QK_SCALE, row[1] * QK_SCALE);
        o.u[1] = pk_u(row[2] * QK_SCALE, row[3] * QK_SCALE);
        o.u[2] = pk_u(row[4] * QK_SCALE, row[5] * QK_SCALE);
        o.u[3] = pk_u(row[6] * QK_SCALE, row[7] * QK_SCALE);
        *(h16x8*)(dst + t * DHEAD + j * 8) = o.v;
    }
}

// ---------- attention ----------
__global__ __launch_bounds__(256, 4)
void attn(const float* __restrict__ qkv, const _Float16* __restrict__ kt,
          float* __restrict__ out) {
    __shared__ alignas(16) _Float16 Ks[2][64 * 64];   // fp16 K^T tile [s][c], swizzled, scaled
    __shared__ alignas(16) _Float16 Vs[2][64 * 64];   // fp16 V tile [c][s], swizzled

    const int tid  = threadIdx.x;
    const int wave = tid >> 6;
    const int lane = tid & 63;
    const int h    = lane >> 5;    // 32x32 MFMA half
    const int c32  = lane & 31;

    // bijective XCD swizzle over 1024 blocks: head b -> XCD (b&7);
    // flat = x + 8*q, x = b&7, q = (b>>3)*16 + tile.
    const int flat = blockIdx.x + (int)gridDim.x * blockIdx.y;  // gridDim.x = 16
    const int b    = (((flat >> 7) & 7) << 3) | (flat & 7);
    const int t0   = ((flat >> 3) & 15) * BQ + wave * 32;

    const float* qg = qkv + ((size_t)b * 3 + 0) * DHEAD * TLEN;
    const float* vg = qkv + ((size_t)b * 3 + 2) * DHEAD * TLEN;
    const _Float16* kb = kt + (size_t)b * DHEAD * TLEN;

    // ---- hoist Q B-frags: B[k=c][n=t], lane (h,c32) holds Q[t0+c32][kbq*16+h*8+j]
    h16x8 qf[4];
    #pragma unroll
    for (int kbq = 0; kbq < 4; ++kbq) {
        const float* qp = qg + (size_t)(kbq * 16 + h * 8) * TLEN + t0 + c32;
        FRAG f;
        #pragma unroll
        for (int w = 0; w < 4; ++w)
            f.u[w] = pk_u(qp[(size_t)(2 * w) * TLEN] * QK_SCALE,
                          qp[(size_t)(2 * w + 1) * TLEN] * QK_SCALE);
        qf[kbq] = f.v;
    }

    f32x16 acco[2];
    #pragma unroll
    for (int cb = 0; cb < 2; ++cb)
        #pragma unroll
        for (int r = 0; r < 16; ++r) acco[cb][r] = 0.f;
    float lp = 0.f;

    // staging map: thread -> (row, 16-elem chunk). Same map for Ks and Vs.
    const int sr = tid >> 2;           // Ks: s row   | Vs: c row
    const int sq = (tid & 3) * 16;     // chunk base

    h16x8 kc2[2], vc2[2];

    auto PREF = [&](int s0) {
        const _Float16* kp = kb + (size_t)(s0 + sr) * DHEAD + sq;
        kc2[0] = *(const h16x8*)(kp);
        kc2[1] = *(const h16x8*)(kp + 8);
        const float* vp = vg + (size_t)sr * TLEN + s0 + sq;
        float4 v0 = *(const float4*)(vp + 0);
        float4 v1 = *(const float4*)(vp + 4);
        float4 v2 = *(const float4*)(vp + 8);
        float4 v3 = *(const float4*)(vp + 12);
        FRAG a, c;
        a.u[0] = pk_u(v0.x, v0.y); a.u[1] = pk_u(v0.z, v0.w);
        a.u[2] = pk_u(v1.x, v1.y); a.u[3] = pk_u(v1.z, v1.w);
        c.u[0] = pk_u(v2.x, v2.y); c.u[1] = pk_u(v2.z, v2.w);
        c.u[2] = pk_u(v3.x, v3.y); c.u[3] = pk_u(v3.z, v3.w);
        vc2[0] = a.v; vc2[1] = c.v;
    };

    PREF(0);

    for (int it = 0; it < NT; ++it) {
        _Float16* ksb = Ks[it & 1];
        _Float16* vsb = Vs[it & 1];
        // write tile it into buf[it&1]; its last readers ran at tile it-2,
        // fenced by the barriers of it-1 and it -> no pre-write barrier.
        *(h16x8*)&ksb[swz(sr, sq)]     = kc2[0];
        *(h16x8*)&ksb[swz(sr, sq + 8)] = kc2[1];
        *(h16x8*)&vsb[swz(sr, sq)]     = vc2[0];
        *(h16x8*)&vsb[swz(sr, sq + 8)] = vc2[1];
        __syncthreads();                       // publish tile it

        if (it + 1 < NT) PREF((it + 1) * BK);  // in flight across compute

        #pragma unroll
        for (int mb = 0; mb < 2; ++mb) {
            // ---- S^T = K^T Q : D[m=s][n=t], lane holds rows (r&3)+8*(r>>2)+4h
            f32x16 accs;
            #pragma unroll
            for (int r = 0; r < 16; ++r) accs[r] = 0.f;

            __builtin_amdgcn_s_setprio(1);
            #pragma unroll
            for (int kbq = 0; kbq < 4; ++kbq) {
                h16x8 ka = *(const h16x8*)&ksb[swz(mb * 32 + c32, kbq * 16 + h * 8)];
                accs = __builtin_amdgcn_mfma_f32_32x32x16_f16(ka, qf[kbq], accs, 0, 0, 0);
            }
            __builtin_amdgcn_s_setprio(0);

            // ---- softmax numerator (exp2, scale pre-folded) + in-register
            // B-frag rebuild: 8x pkrtz + 4x permlane32_swap per 32x32 block.
            float e[16];
            #pragma unroll
            for (int r = 0; r < 16; ++r) e[r] = __ocml_native_exp2_f32(accs[r]);
            float s0 = 0.f;
            #pragma unroll
            for (int r = 0; r < 16; ++r) s0 += e[r];
            lp += s0;

            h16x8 pb[2];   // [kb16]
            #pragma unroll
            for (int kb16 = 0; kb16 < 2; ++kb16) {
                const float* ee = e + kb16 * 8;
                unsigned a01 = pk_u(ee[0], ee[1]);
                unsigned a23 = pk_u(ee[2], ee[3]);
                unsigned b01 = pk_u(ee[4], ee[5]);
                unsigned b23 = pk_u(ee[6], ee[7]);
                asm volatile("v_permlane32_swap_b32 %0, %1" : "+v"(a01), "+v"(b01));
                asm volatile("v_permlane32_swap_b32 %0, %1" : "+v"(a23), "+v"(b23));
                FRAG f;
                f.u[0] = a01; f.u[1] = a23; f.u[2] = b01; f.u[3] = b23;
                pb[kb16] = f.v;
            }

            // ---- O^T += V P^T : A = Vs rows, B = pb (registers, no LDS)
            __builtin_amdgcn_s_setprio(1);
            #pragma unroll
            for (int kb16 = 0; kb16 < 2; ++kb16) {
                const int scol = mb * 32 + kb16 * 16 + h * 8;
                #pragma unroll
                for (int cb = 0; cb < 2; ++cb) {
                    h16x8 va = *(const h16x8*)&vsb[swz(cb * 32 + c32, scol)];
                    acco[cb] = __builtin_amdgcn_mfma_f32_32x32x16_f16(va, pb[kb16], acco[cb], 0, 0, 0);
                }
            }
            __builtin_amdgcn_s_setprio(0);
        }
    }

    // ---- finalize: lane h and h^1 (xor 32) hold complementary s-rows
    float l = lp;
    l += __shfl_xor(l, 32);
    const float rinv = 1.0f / l;

    float* ob = out + (size_t)b * DHEAD * TLEN + t0;
    #pragma unroll
    for (int cb = 0; cb < 2; ++cb)
        #pragma unroll
        for (int r = 0; r < 16; ++r) {
            const int c = cb * 32 + (r & 3) + 8 * (r >> 2) + 4 * h;
            ob[(size_t)c * TLEN + c32] = acco[cb][r] * rinv;
        }
}

extern "C" void kernel_launch(void* const* d_in, const int* in_sizes, int n_in,
                              void* d_out, int out_size, void* d_ws, size_t ws_size,
                              hipStream_t stream) {
    const float* qkv = (const float*)d_in[0];
    _Float16* ws = (_Float16*)d_ws;   // Kt: 64*64*2048*2 B = 16.8 MB
    float* out = (float*)d_out;
    prep_k<<<dim3(TLEN / 64, NB), 256, 0, stream>>>(qkv, ws);
    attn<<<dim3(TLEN / BQ, NB), 256, 0, stream>>>(qkv, ws, out);
}